// Round 1
// 400.423 us; speedup vs baseline: 1.0276x; 1.0276x over previous
//
#include <hip/hip_runtime.h>
#include <math.h>

#define M   24
#define TS  60
#define NX  192
#define NY  192
#define H_  4
#define D_  8
#define NTS 50   // N_TIME_STEPS
#define NG  50

// Setup results computed by prep_kernel each call (always fully rewritten —
// no cross-call state dependence).
__device__ float g_w[M];
__device__ int   g_ti[NTS][M];
__device__ int   g_ix[NG];
__device__ float g_fx[NG];
__device__ float g_mx[NG];
__device__ int   g_iy[M][NG];
__device__ float g_fy[M][NG];
__device__ float g_my[M][NG];

__global__ __launch_bounds__(256) void prep_kernel(
    const float* __restrict__ params, const float* __restrict__ src_y,
    const float* __restrict__ stl,
    const float* __restrict__ Wq, const float* __restrict__ bq,
    const float* __restrict__ Wk, const float* __restrict__ bk,
    const float* __restrict__ lyt_p, const float* __restrict__ ccu_p,
    const float* __restrict__ cni_p)
{
    const int tid = threadIdx.x;
    __shared__ float s_logits[M][H_];
    __shared__ float s_sw[M];
    __shared__ float s_eh[H_][M];   // per-head softmax result e/s

    const float ly_target = lyt_p[0];

    const float t_ly = (ly_target - 30.0f) / 90.0f;
    const float t_cu = ccu_p[0] / 0.0029f;
    const float t_ni = cni_p[0] / 0.0018f;

    // ---- per-m logits + similarity weight ----
    if (tid < M) {
        const int m = tid;
        const float ly  = params[m*3 + 0];
        const float ccu = params[m*3 + 1];
        const float cni = params[m*3 + 2];
        const float ly_n = (ly - 30.0f) / 90.0f;
        const float cu_n = ccu / 0.0029f;
        const float ni_n = cni / 0.0018f;
        for (int h = 0; h < H_; ++h) {
            float acc = 0.0f;
            for (int d = 0; d < D_; ++d) {
                const int col = h*D_ + d;
                const float q = t_ly*Wq[0*32+col] + t_cu*Wq[1*32+col] + t_ni*Wq[2*32+col] + bq[col];
                const float k = ly_n*Wk[0*32+col] + cu_n*Wk[1*32+col] + ni_n*Wk[2*32+col] + bk[col];
                acc += k * q;
            }
            s_logits[m][h] = acc / sqrtf(8.0f);
        }
        const float dly = ly_n - t_ly, dcu = cu_n - t_cu, dni = ni_n - t_ni;
        const float d2 = (dly*dly + dcu*dcu + dni*dni) / 0.04f;
        s_sw[m] = expf(-d2 * 0.5f);
    }
    __syncthreads();

    // ---- per-head softmax in parallel (h = tid) ----
    if (tid < H_) {
        const int h = tid;
        float mxv = -1e30f;
        for (int m = 0; m < M; ++m) mxv = fmaxf(mxv, s_logits[m][h]);
        float e[M]; float s = 0.0f;
        for (int m = 0; m < M; ++m) { e[m] = expf(s_logits[m][h] - mxv); s += e[m]; }
        for (int m = 0; m < M; ++m) s_eh[h][m] = e[m] / s;
    }
    __syncthreads();

    if (tid == 0) {
        float ssw = 0.0f;
        for (int m = 0; m < M; ++m) ssw += s_sw[m];
        float w[M]; float wsum = 0.0f;
        for (int m = 0; m < M; ++m) {
            float attn = 0.0f;
            for (int h = 0; h < H_; ++h) attn += s_eh[h][m];
            w[m] = (attn * 0.25f) * (s_sw[m] / (ssw + 1e-12f));
            wsum += w[m];
        }
        for (int m = 0; m < M; ++m) g_w[m] = w[m] / (wsum + 1e-12f);
    }

    // ---- ti[t][m] : banker's rounding to match jnp.round ----
    const float step_t = 200.0f / 49.0f;
    for (int idx = tid; idx < NTS*M; idx += blockDim.x) {
        const int t = idx / M, m = idx % M;
        const float tt = (t == NTS-1) ? 200.0f : step_t * (float)t;
        const float r = tt / stl[m] * 59.0f;
        int ti = (int)rintf(r);
        ti = ti < 0 ? 0 : (ti > TS-1 ? TS-1 : ti);
        g_ti[t][m] = ti;
    }

    // ---- x-axis interp setup: binary upper_bound on computed uniform grid ----
    // grid value gv(g) = (g==NX-1) ? 100 : step_x*g  (monotone increasing)
    if (tid < NG) {
        const int i = tid;
        const float step_x = 100.0f / 191.0f;
        const float step_q = 100.0f / 49.0f;
        const float q = (i == NG-1) ? 100.0f : step_q * (float)i;
        int lo = 0, hi = NX;          // lo = count of grid elems <= q
        while (lo < hi) {
            const int mid = (lo + hi) >> 1;
            const float gv = (mid == NX-1) ? 100.0f : step_x * (float)mid;
            if (gv <= q) lo = mid + 1; else hi = mid;
        }
        int id = lo - 1;
        id = id < 0 ? 0 : (id > NX-2 ? NX-2 : id);
        const float g0 = (id   == NX-1) ? 100.0f : step_x * (float)id;
        const float g1 = (id+1 == NX-1) ? 100.0f : step_x * (float)(id+1);
        g_ix[i] = id;
        g_fx[i] = (q - g0) / (g1 - g0);
        g_mx[i] = (q >= 0.0f && q <= 100.0f) ? 1.0f : 0.0f;
    }

    // ---- y-axis interp setup per m: binary upper_bound on sy[g]*scale ----
    for (int idx = tid; idx < M*NG; idx += blockDim.x) {
        const int m = idx / NG, j = idx % NG;
        const float scale = ly_target / params[m*3 + 0];   // IEEE fp32 div, matches ref
        const float q = (float)j / 49.0f * ly_target;
        const float* sy = src_y + m*NY;
        int lo = 0, hi = NY;          // lo = count of scaled grid elems <= q
        while (lo < hi) {
            const int mid = (lo + hi) >> 1;
            const float gv = sy[mid] * scale;              // IEEE fp32 mul, matches ref
            if (gv <= q) lo = mid + 1; else hi = mid;
        }
        int id = lo - 1;
        id = id < 0 ? 0 : (id > NY-2 ? NY-2 : id);
        const float g0 = sy[id] * scale;
        const float g1 = sy[id+1] * scale;
        g_iy[m][j] = id;
        g_fy[m][j] = (q - g0) / (g1 - g0);
        const float gfirst = sy[0] * scale;
        const float glast  = sy[NY-1] * scale;
        g_my[m][j] = (q >= gfirst && q <= glast) ? 1.0f : 0.0f;
    }
}

// One thread computes BOTH fields (f=0,1) for its (t,i,j): shares all index
// math/table reads and doubles independent loads in flight.
__global__ __launch_bounds__(256) void interp_kernel(
    const float* __restrict__ c1, const float* __restrict__ c2,
    float* __restrict__ out,
    const float* __restrict__ ccu_p, const float* __restrict__ cni_p)
{
    const int t   = blockIdx.y;
    const int tid = threadIdx.x;

    // Block-local staging of all per-(m,j) tables + per-(t,m) slice offsets.
    __shared__ int   s_off[M];        // (m*TS + ti[t][m]) * NX*NY
    __shared__ float s_w[M];
    __shared__ int   s_iy[M][NG];
    __shared__ float s_fy[M][NG];
    __shared__ float s_my[M][NG];

    if (tid < M) {
        s_off[tid] = (tid*TS + g_ti[t][tid]) * (NX*NY);
        s_w[tid]   = g_w[tid];
    }
    for (int idx = tid; idx < M*NG; idx += 256) {
        const int m = idx / NG, j = idx % NG;
        s_iy[m][j] = g_iy[m][j];
        s_fy[m][j] = g_fy[m][j];
        s_my[m][j] = g_my[m][j];
    }
    __syncthreads();

    const int p = blockIdx.x * 256 + tid;
    if (p >= NG*NG) return;
    const int i = p / NG;
    const int j = p % NG;

    const int   ixNY = g_ix[i] * NY;
    const float fxi  = g_fx[i];
    const float mxi  = g_mx[i];

    float acc0 = 0.0f;
    float acc1 = 0.0f;
    #pragma unroll 8
    for (int m = 0; m < M; ++m) {
        const int   off = s_off[m] + ixNY + s_iy[m][j];
        const float fyj = s_fy[m][j];
        const float msk = mxi * s_my[m][j];
        const float wm  = s_w[m];

        const float* __restrict__ b1 = c1 + off;
        const float* __restrict__ b2 = c2 + off;

        const float a00 = b1[0];
        const float a01 = b1[1];
        const float a10 = b1[NY];
        const float a11 = b1[NY + 1];
        const float b00 = b2[0];
        const float b01 = b2[1];
        const float b10 = b2[NY];
        const float b11 = b2[NY + 1];

        const float ax0 = a00*(1.0f - fxi) + a10*fxi;
        const float ax1 = a01*(1.0f - fxi) + a11*fxi;
        const float av  = (ax0*(1.0f - fyj) + ax1*fyj) * msk;
        acc0 += av * wm;

        const float bx0 = b00*(1.0f - fxi) + b10*fxi;
        const float bx1 = b01*(1.0f - fxi) + b11*fxi;
        const float bv  = (bx0*(1.0f - fyj) + bx1*fyj) * msk;
        acc1 += bv * wm;
    }

    if (j == 0)      acc0 = ccu_p[0];
    if (j == NG-1)   acc1 = cni_p[0];

    out[(((size_t)0*NTS + t)*NG + i)*NG + j] = acc0;
    out[(((size_t)1*NTS + t)*NG + i)*NG + j] = acc1;
}

extern "C" void kernel_launch(void* const* d_in, const int* in_sizes, int n_in,
                              void* d_out, int out_size, void* d_ws, size_t ws_size,
                              hipStream_t stream) {
    const float* c1     = (const float*)d_in[0];
    const float* c2     = (const float*)d_in[1];
    const float* params = (const float*)d_in[2];
    const float* src_y  = (const float*)d_in[3];
    const float* stl    = (const float*)d_in[4];
    const float* Wq     = (const float*)d_in[5];
    const float* bq     = (const float*)d_in[6];
    const float* Wk     = (const float*)d_in[7];
    const float* bk     = (const float*)d_in[8];
    const float* lyt    = (const float*)d_in[9];
    const float* ccut   = (const float*)d_in[10];
    const float* cnit   = (const float*)d_in[11];
    float* out = (float*)d_out;

    prep_kernel<<<1, 256, 0, stream>>>(params, src_y, stl, Wq, bq, Wk, bk, lyt, ccut, cnit);

    dim3 grid((NG*NG + 255) / 256, NTS, 1);
    interp_kernel<<<grid, 256, 0, stream>>>(c1, c2, out, ccut, cnit);
}